// Round 4
// baseline (26.552 us; speedup 1.0000x reference)
//
#include <hip/hip_runtime.h>
#include <math.h>

#define HH 256
#define WW 256
#define NF 352
#define NV 192
#define SIGMA_F 0.7f
#define CUT_S (-16.0f)

__device__ __forceinline__ float fast_sigmoid(float x) {
    // 1/(1+exp(-x)); large |x| saturates correctly (exp->inf => 0, exp->0 => 1)
    return __builtin_amdgcn_rcpf(1.0f + __expf(-x));
}

// One block = one 16x16 pixel tile; each of the 4 waves owns an 8x8 subtile.
// Numerics identical to the R2-proven kernel (natural-log domain, per-edge
// sigmoid, IEEE divide in projection). Only the cull granularity is per-wave.
__global__ __launch_bounds__(256) void sil_tile_kernel(
    const float* __restrict__ Rm, const float* __restrict__ obj_t,
    const float* __restrict__ obj_s, const float* __restrict__ verts,
    const int* __restrict__ faces, const float* __restrict__ Km,
    const float* __restrict__ keep_mask, const float* __restrict__ image_ref,
    const float* __restrict__ iref_src, const float* __restrict__ edt_src,
    float* __restrict__ out_image, float* __restrict__ loss_partials,
    float* __restrict__ out_iref, float* __restrict__ out_edt)
{
    __shared__ float co[NF * 9];              // natural-domain edge coefficients
    __shared__ unsigned short flist[4][NF];   // per-subtile surviving faces
    __shared__ int fcount[4];
    __shared__ float wsum[4];

    const int tid  = threadIdx.x;
    const int lane = tid & 63;
    const int wv   = tid >> 6;
    const int b    = blockIdx.x >> 8;     // 256 tiles per batch image
    const int t    = blockIdx.x & 255;
    const int x0   = (t & 15) * 16, y0 = (t >> 4) * 16;

    // ---- phase 1: per-face edge coefficients (identical to R2) ----
    const float* Rb = Rm + b * 9;
    const float s  = obj_s[b];
    const float t0 = obj_t[b*3+0], t1 = obj_t[b*3+1], t2 = obj_t[b*3+2];
    const float K00 = Km[b*9+0], K02 = Km[b*9+2], K11 = Km[b*9+4], K12 = Km[b*9+5];

    for (int f = tid; f < NF; f += 256) {
        float X[3], Y[3];
        #pragma unroll
        for (int k = 0; k < 3; ++k) {
            int vi = faces[f*3 + k];
            const float* vp = verts + (b * NV + vi) * 3;
            float v0 = vp[0], v1 = vp[1], v2 = vp[2];
            float w0 = s * (v0*Rb[0] + v1*Rb[3] + v2*Rb[6] + t0);
            float w1 = s * (v0*Rb[1] + v1*Rb[4] + v2*Rb[7] + t1);
            float w2 = s * (v0*Rb[2] + v1*Rb[5] + v2*Rb[8] + t2);
            X[k] = (K00 * w0 / w2 + K02) * (float)WW;
            Y[k] = (K11 * w1 / w2 + K12) * (float)HH;
        }
        float e01x = X[1]-X[0], e01y = Y[1]-Y[0];
        float e02x = X[2]-X[0], e02y = Y[2]-Y[0];
        float area2 = e01x*e02y - e01y*e02x;
        float orient = (area2 >= 0.0f) ? 1.0f : -1.0f;
        #pragma unroll
        for (int k = 0; k < 3; ++k) {
            int k1 = (k == 2) ? 0 : k + 1;
            float ax = X[k], ay = Y[k];
            float ex = X[k1]-ax, ey = Y[k1]-ay;
            float inv = orient / (sqrtf(ex*ex + ey*ey) + 1e-8f) / SIGMA_F;
            co[f*9 + k*3 + 0] = ex * inv;               // A (coeff of py)
            co[f*9 + k*3 + 1] = -ey * inv;              // B (coeff of px)
            co[f*9 + k*3 + 2] = inv * (ey*ax - ex*ay);  // C
        }
    }
    __syncthreads();

    // ---- phase 2: per-wave subtile cull + ordered compaction ----
    const int sx = (wv & 1) * 8, sy = (wv >> 1) * 8;
    const float pxc = (float)(x0 + sx) + 4.0f;   // subtile center (half-ext 3.5<=4)
    const float pyc = (float)(y0 + sy) + 4.0f;
    {
        int base = 0;
        #pragma unroll
        for (int r = 0; r < 6; ++r) {            // 6*64 = 384 >= NF
            int f = r * 64 + lane;
            bool keep = false;
            if (f < NF) {
                float smin = 1e30f;
                #pragma unroll
                for (int k = 0; k < 3; ++k) {
                    float A = co[f*9 + k*3 + 0];
                    float B = co[f*9 + k*3 + 1];
                    float C = co[f*9 + k*3 + 2];
                    // exact max of affine s over subtile rect (center +- 4)
                    float smax = fmaf(A, pyc, fmaf(B, pxc, C)) + 4.0f*(fabsf(A) + fabsf(B));
                    smin = fminf(smin, smax);
                }
                // if some edge has s <= -16 everywhere, prob <= sigmoid(-16) ~ 1.1e-7
                keep = (smin > CUT_S);
            }
            unsigned long long m = __ballot(keep);
            if (keep) {
                int pre = __popcll(m & ((1ull << lane) - 1ull));
                flist[wv][base + pre] = (unsigned short)f;
            }
            base += __popcll(m);
        }
        if (lane == 0) fcount[wv] = base;
    }
    __syncthreads();   // insurance: make compaction globally visible

    // ---- phase 3: per-lane pixel, loop surviving faces (R2 numerics) ----
    const int n  = fcount[wv];
    const int lx = lane & 7, ly = lane >> 3;
    const float px = (float)(x0 + sx + lx) + 0.5f;
    const float py = (float)(y0 + sy + ly) + 0.5f;
    float acc = 1.0f;
    for (int i = 0; i < n; ++i) {
        const float* c = &co[(int)flist[wv][i] * 9];
        float s0 = fmaf(c[0], py, fmaf(c[1], px, c[2]));
        float s1 = fmaf(c[3], py, fmaf(c[4], px, c[5]));
        float s2 = fmaf(c[6], py, fmaf(c[7], px, c[8]));
        float p = fast_sigmoid(s0) * fast_sigmoid(s1) * fast_sigmoid(s2);
        p = fminf(p, 0.9999f);      // clip(prob, 0, 1-1e-4); p >= 0 already
        acc *= (1.0f - p);
    }
    float sil = 1.0f - acc;
    const int gidx = b * (HH*WW) + (y0 + sy + ly) * WW + (x0 + sx + lx);
    float img = keep_mask[gidx] * sil;
    out_image[gidx] = img;

    // ---- passthrough copies (coalesced) ----
    const int g = blockIdx.x * 256 + tid;
    out_iref[g] = iref_src[g];
    out_edt[g]  = edt_src[g];

    // ---- masked L2 loss partial: fixed-tree deterministic reduction ----
    float d = img - image_ref[gidx];
    float sq = d * d;
    #pragma unroll
    for (int o = 32; o > 0; o >>= 1) sq += __shfl_down(sq, o);
    if (lane == 0) wsum[wv] = sq;
    __syncthreads();
    if (tid == 0) loss_partials[blockIdx.x] = wsum[0] + wsum[1] + wsum[2] + wsum[3];
}

// edges (separable 7x7 maxpool - image) + final loss reduce in block 0.
__global__ __launch_bounds__(256) void post_kernel(
    const float* __restrict__ image, const float* __restrict__ partials,
    float* __restrict__ out_loss, float* __restrict__ out_edges)
{
    __shared__ float tile[22][23];     // 16+2*3 halo, +1 col pad
    __shared__ float rmax[22][16];     // row-max over 7-wide window
    __shared__ float lsum[4];

    const int tid = threadIdx.x;
    const int b   = blockIdx.x >> 8;
    const int t   = blockIdx.x & 255;
    const int x0  = (t & 15) * 16, y0 = (t >> 4) * 16;
    const float* im = image + b * (HH*WW);

    // load 22x22 halo tile (OOB -> -inf; window always contains center pixel)
    for (int i = tid; i < 22*22; i += 256) {
        int r = i / 22, cidx = i % 22;
        int yy = y0 + r - 3, xx = x0 + cidx - 3;
        float v = -INFINITY;
        if (yy >= 0 && yy < HH && xx >= 0 && xx < WW) v = im[yy * WW + xx];
        tile[r][cidx] = v;
    }
    __syncthreads();

    // row pass
    for (int i = tid; i < 22*16; i += 256) {
        int r = i >> 4, c = i & 15;
        float m = tile[r][c];
        #pragma unroll
        for (int d = 1; d < 7; ++d) m = fmaxf(m, tile[r][c + d]);
        rmax[r][c] = m;
    }
    __syncthreads();

    // col pass + write edges
    const int lx = tid & 15, ly = tid >> 4;
    float m = rmax[ly][lx];
    #pragma unroll
    for (int d = 1; d < 7; ++d) m = fmaxf(m, rmax[ly + d][lx]);
    const int gidx = b * (HH*WW) + (y0 + ly) * WW + (x0 + lx);
    out_edges[gidx] = m - tile[ly + 3][lx + 3];

    // final loss reduction (block 0 only)
    if (blockIdx.x == 0) {
        float v = partials[tid] + partials[tid + 256];
        #pragma unroll
        for (int o = 32; o > 0; o >>= 1) v += __shfl_down(v, o);
        if ((tid & 63) == 0) lsum[tid >> 6] = v;
        __syncthreads();
        if (tid == 0)
            out_loss[0] = (lsum[0] + lsum[1] + lsum[2] + lsum[3]) * 0.5f; // mean over B=2
    }
}

extern "C" void kernel_launch(void* const* d_in, const int* in_sizes, int n_in,
                              void* d_out, int out_size, void* d_ws, size_t ws_size,
                              hipStream_t stream) {
    const float* Rm    = (const float*)d_in[0];
    const float* obj_t = (const float*)d_in[1];
    const float* obj_s = (const float*)d_in[2];
    const float* verts = (const float*)d_in[3];
    const int*   faces = (const int*)d_in[4];
    const float* Km    = (const float*)d_in[5];
    const float* keep  = (const float*)d_in[6];
    const float* iref  = (const float*)d_in[7];
    const float* edt   = (const float*)d_in[8];

    float* out       = (float*)d_out;
    float* out_loss  = out;
    float* out_image = out + 1;
    float* out_edges = out + 1 + 131072;
    float* out_iref  = out + 1 + 262144;
    float* out_edt   = out + 1 + 393216;
    float* partials  = (float*)d_ws;      // 512 floats

    sil_tile_kernel<<<512, 256, 0, stream>>>(Rm, obj_t, obj_s, verts, faces, Km,
                                             keep, iref, iref, edt,
                                             out_image, partials, out_iref, out_edt);
    post_kernel<<<512, 256, 0, stream>>>(out_image, partials, out_loss, out_edges);
}